// Round 2
// baseline (708.707 us; speedup 1.0000x reference)
//
#include <hip/hip_runtime.h>

typedef _Float16 half8 __attribute__((ext_vector_type(8)));
typedef _Float16 half4 __attribute__((ext_vector_type(4)));
typedef float    floatx16 __attribute__((ext_vector_type(16)));

#define MFMA(a, b, c) __builtin_amdgcn_mfma_f32_32x32x16_f16((a), (b), (c), 0, 0, 0)

constexpr int NB = 32, NC = 256, NL = 1024, MI = 32, BJ = 32;
constexpr int NIT = NL / BJ;   // 32
constexpr int PSP = 33;        // pS row pitch (floats): <=2-way banks, scalar reads

// LDS byte offsets (total 52096 -> 3 blocks/CU: 3*52096 = 156288 <= 163840)
constexpr int OFF_V    = 0;        // vF  f16 [8 ct][2 ksj][64 ls][8 t] = 16384 (swizzled granules)
constexpr int OFF_S    = 16384;    // sF  same = 16384
constexpr int OFF_PS   = 32768;    // pS  f32 [4 w][32 i][33] = 16896
constexpr int OFF_PB   = 49664;    // pB  f16 [2 ksj][64 ls][8 t] = 2048
constexpr int OFF_ROWS = 51712;    // m/l/a rows 3*32*4 = 384
constexpr int SMEM_B   = 52096;

// Granule swizzle: XOR the two "j-chunk" bits (granule bits 5-6) into bits 1-2 so the
// 4 jc-variants of one c-row land in different bank quads. Applied on write AND read.
__device__ __forceinline__ int swz(int g) { return g ^ (((g >> 5) & 3) << 1); }

__global__ __launch_bounds__(256, 3)
void att_mfma4(const float* __restrict__ q,
               const float* __restrict__ kk,
               const float* __restrict__ v,
               const float* __restrict__ sd,
               const float* __restrict__ bt,
               const int* __restrict__ ri,
               float* __restrict__ out)
{
    __shared__ __align__(16) char smem[SMEM_B];
    _Float16* vH   = (_Float16*)(smem + OFF_V);
    _Float16* sH   = (_Float16*)(smem + OFF_S);
    float*    pS   = (float*)(smem + OFF_PS);
    _Float16* pB   = (_Float16*)(smem + OFF_PB);
    float*    mrow = (float*)(smem + OFF_ROWS);
    float*    lrow = mrow + 32;
    float*    arow = mrow + 64;

    const int tid  = threadIdx.x;
    const int lane = tid & 63;
    const int wv   = tid >> 6;

    // XCD-locality swizzle: one batch's 32 i-blocks cluster on one XCD.
    const int bid = blockIdx.x;
    const int b   = (bid & 7) + ((bid >> 8) << 3);
    const int ib  = (bid >> 3) & 31;
    const int i0  = ib * MI;

    const float* kbase = kk + (size_t)b * NC * NL;
    const float* vbase = v  + (size_t)b * NC * NL;
    const float* sbase = sd + (size_t)b * NC * NL;

    // ---- Q A-fragments (hi/lo fp16). Wave wv owns ks = wv*4 .. wv*4+3 (channels wv*64..wv*64+63)
    half8 qhi[4], qlo[4];
    {
        const float* qb = q + (size_t)b * NC * NL + i0 + (lane & 31);
        #pragma unroll
        for (int kq = 0; kq < 4; ++kq) {
            const int c0 = (wv * 4 + kq) * 16 + (lane >> 5) * 8;
            #pragma unroll
            for (int t = 0; t < 8; ++t) {
                float x = qb[(size_t)(c0 + t) * NL];
                _Float16 h = (_Float16)x;
                qhi[kq][t] = h;
                qlo[kq][t] = (_Float16)(x - (float)h);
            }
        }
    }
    if (tid < 32) { mrow[tid] = -1e30f; lrow[tid] = 0.0f; arow[tid] = 1.0f; }

    // ---- staging geometry (V/SD): coalesced global reads, swizzled conflict-free b128 writes
    int co[4], swg[4];
    #pragma unroll
    for (int r = 0; r < 4; ++r) {
        const int c = (tid >> 2) + r * 64, jc = tid & 3;
        co[r] = c * NL + jc * 8;
        const int gr = ((c >> 5) * 2 + (jc >> 1)) * 64 + (jc & 1) * 32 + (c & 31);
        swg[r] = swz(gr) * 8;
    }
    // PV read offsets (half units), same swizzle
    int gA[2][2];
    #pragma unroll
    for (int d = 0; d < 2; ++d)
        #pragma unroll
        for (int ksj = 0; ksj < 2; ++ksj)
            gA[d][ksj] = swz(((wv * 2 + d) * 2 + ksj) * 64 + lane) * 8;

    floatx16 aV[2], aS[2];
    #pragma unroll
    for (int d = 0; d < 2; ++d)
        #pragma unroll
        for (int r = 0; r < 16; ++r) { aV[d][r] = 0.f; aS[d][r] = 0.f; }

    auto pv_step = [&]() {
        const float al = arow[lane & 31];
        if (!__all(al == 1.0f)) {   // exact: skip is bitwise-identical when max unchanged
            #pragma unroll
            for (int d = 0; d < 2; ++d)
                #pragma unroll
                for (int r = 0; r < 16; ++r) { aV[d][r] *= al; aS[d][r] *= al; }
        }
        half8 pb0 = *(const half8*)(pB + lane * 8);
        half8 pb1 = *(const half8*)(pB + (64 + lane) * 8);
        #pragma unroll
        for (int d = 0; d < 2; ++d) {
            half8 a0 = *(const half8*)(vH + gA[d][0]);
            half8 a1 = *(const half8*)(vH + gA[d][1]);
            aV[d] = MFMA(a0, pb0, aV[d]);
            aV[d] = MFMA(a1, pb1, aV[d]);
            half8 b0 = *(const half8*)(sH + gA[d][0]);
            half8 b1 = *(const half8*)(sH + gA[d][1]);
            aS[d] = MFMA(b0, pb0, aS[d]);
            aS[d] = MFMA(b1, pb1, aS[d]);
        }
    };

    for (int it = 0; it < NIT; ++it) {
        const int j0 = it * BJ;
        const float* kcol = kbase + j0 + (lane & 31);

        // ---- K fragments, direct global->reg, 2-deep pipeline (cap register residency).
        // Pair 0/1 issued here (latency hides under PV); pair 2/3 issued inside scores.
        float kr[2][8];
        #pragma unroll
        for (int p = 0; p < 2; ++p) {
            const int c0 = (wv * 4 + p) * 16 + (lane >> 5) * 8;
            #pragma unroll
            for (int t = 0; t < 8; ++t)
                kr[p][t] = kcol[(size_t)(c0 + t) * NL];
        }

        // ---- PV(it-1): all waves, 2 c-tiles each ----
        if (it > 0) pv_step();

        // ---- scores(it): ALL 4 waves, quarter-C partials each ----
        {
            floatx16 S;
            #pragma unroll
            for (int r = 0; r < 16; ++r) S[r] = 0.f;
            #pragma unroll
            for (int kq = 0; kq < 4; ++kq) {
                half8 bf;
                #pragma unroll
                for (int t = 0; t < 8; ++t) bf[t] = (_Float16)kr[kq & 1][t];
                if (kq < 2) {   // refill this buffer with kq+2
                    const int c0 = (wv * 4 + kq + 2) * 16 + (lane >> 5) * 8;
                    #pragma unroll
                    for (int t = 0; t < 8; ++t)
                        kr[kq & 1][t] = kcol[(size_t)(c0 + t) * NL];
                }
                S = MFMA(qhi[kq], bf, S);
                S = MFMA(qlo[kq], bf, S);
            }
            float* ps = pS + wv * 32 * PSP + (lane & 31);
            #pragma unroll
            for (int r = 0; r < 16; ++r) {
                const int row = (r & 3) + 8 * (r >> 2) + 4 * (lane >> 5);
                ps[row * PSP] = S[r];
            }
        }
        __syncthreads();   // B1: pS ready; vF/sF/pB old reads done

        // ---- stage V/SD(it): load -> convert -> swizzled write (low reg residency) ----
        #pragma unroll
        for (int r = 0; r < 4; ++r) {
            const float* src = vbase + co[r] + j0;
            float4 a = *(const float4*)(src);
            float4 c = *(const float4*)(src + 4);
            half8 h;
            h[0] = (_Float16)a.x; h[1] = (_Float16)a.y; h[2] = (_Float16)a.z; h[3] = (_Float16)a.w;
            h[4] = (_Float16)c.x; h[5] = (_Float16)c.y; h[6] = (_Float16)c.z; h[7] = (_Float16)c.w;
            *(half8*)(vH + swg[r]) = h;
        }
        #pragma unroll
        for (int r = 0; r < 4; ++r) {
            const float* src = sbase + co[r] + j0;
            float4 a = *(const float4*)(src);
            float4 c = *(const float4*)(src + 4);
            half8 h;
            h[0] = (_Float16)a.x; h[1] = (_Float16)a.y; h[2] = (_Float16)a.z; h[3] = (_Float16)a.w;
            h[4] = (_Float16)c.x; h[5] = (_Float16)c.y; h[6] = (_Float16)c.z; h[7] = (_Float16)c.w;
            *(half8*)(sH + swg[r]) = h;
        }

        // ---- softmax(it): thread (i = tid>>3, s = tid&7) owns 4 cols; sums 4 partials ----
        {
            const int i = tid >> 3, s = tid & 7;
            const int4 r4 = *(const int4*)(ri + (size_t)(i0 + i) * NL + j0 + s * 4);
            const float* p0 = pS + i * PSP + s * 4;
            float sc[4];
            #pragma unroll
            for (int x = 0; x < 4; ++x)
                sc[x] = p0[x] + p0[32 * PSP + x] + p0[64 * PSP + x] + p0[96 * PSP + x];
            sc[0] += bt[r4.x];
            sc[1] += bt[r4.y];
            sc[2] += bt[r4.z];
            sc[3] += bt[r4.w];
            float lm = fmaxf(fmaxf(sc[0], sc[1]), fmaxf(sc[2], sc[3]));
            lm = fmaxf(lm, __shfl_xor(lm, 1));
            lm = fmaxf(lm, __shfl_xor(lm, 2));
            lm = fmaxf(lm, __shfl_xor(lm, 4));
            const float mo = mrow[i];
            const float mn = fmaxf(lm, mo);
            float sum = 0.f;
            half4 ph;
            #pragma unroll
            for (int x = 0; x < 4; ++x) {
                float e = __expf(sc[x] - mn);
                sum += e;
                ph[x] = (_Float16)e;
            }
            sum += __shfl_xor(sum, 1);
            sum += __shfl_xor(sum, 2);
            sum += __shfl_xor(sum, 4);
            // pB frag: B[k=j][n=i], j = 4s..4s+3 -> ksj=s>>2, half=(s>>1)&1, t0=(s&1)*4
            *(half4*)(pB + (((s >> 2) * 64) + ((s >> 1) & 1) * 32 + i) * 8 + (s & 1) * 4) = ph;
            if (s == 0) {
                float al = __expf(mo - mn);   // == 1.0f exactly when mn == mo
                arow[i] = al;
                lrow[i] = lrow[i] * al + sum;
                mrow[i] = mn;
            }
        }
        __syncthreads();   // B2: pB/rows/vF/sF(it) ready
    }

    // ---- drain PV(NIT-1) ----
    pv_step();

    // ---- epilogue: normalize, LDS transpose (scr overlaps dead vF/sF/pS head), coalesced store ----
    const float linv = 1.0f / lrow[lane & 31];
    float* scr = (float*)smem;   // 256*33*4 = 33792 B (< OFF_PB; pB/rows untouched)
    __syncthreads();
    #pragma unroll
    for (int d = 0; d < 2; ++d) {
        const int ct = wv * 2 + d;
        #pragma unroll
        for (int r = 0; r < 16; ++r) {
            int c = ct * 32 + (r & 3) + 8 * (r >> 2) + 4 * (lane >> 5);
            scr[c * 33 + (lane & 31)] = aV[d][r] * linv;
        }
    }
    __syncthreads();
    {
        float* og = out + ((size_t)b * NC + tid) * NL + i0;
        #pragma unroll
        for (int g = 0; g < 8; ++g) {
            float4 o;
            o.x = scr[tid * 33 + g * 4 + 0];
            o.y = scr[tid * 33 + g * 4 + 1];
            o.z = scr[tid * 33 + g * 4 + 2];
            o.w = scr[tid * 33 + g * 4 + 3];
            *(float4*)(og + g * 4) = o;
        }
    }
    __syncthreads();
    #pragma unroll
    for (int d = 0; d < 2; ++d) {
        const int ct = wv * 2 + d;
        #pragma unroll
        for (int r = 0; r < 16; ++r) {
            int c = ct * 32 + (r & 3) + 8 * (r >> 2) + 4 * (lane >> 5);
            scr[c * 33 + (lane & 31)] = aS[d][r] * linv;
        }
    }
    __syncthreads();
    {
        float* og = out + (size_t)NB * NC * NL + ((size_t)b * NC + tid) * NL + i0;
        #pragma unroll
        for (int g = 0; g < 8; ++g) {
            float4 o;
            o.x = scr[tid * 33 + g * 4 + 0];
            o.y = scr[tid * 33 + g * 4 + 1];
            o.z = scr[tid * 33 + g * 4 + 2];
            o.w = scr[tid * 33 + g * 4 + 3];
            *(float4*)(og + g * 4) = o;
        }
    }
}

extern "C" void kernel_launch(void* const* d_in, const int* in_sizes, int n_in,
                              void* d_out, int out_size, void* d_ws, size_t ws_size,
                              hipStream_t stream)
{
    (void)in_sizes; (void)n_in; (void)d_ws; (void)ws_size; (void)out_size;
    const float* q  = (const float*)d_in[0];
    const float* k  = (const float*)d_in[1];
    const float* v  = (const float*)d_in[2];
    const float* s  = (const float*)d_in[3];
    const float* bt = (const float*)d_in[4];
    const int*   ri = (const int*)d_in[5];
    att_mfma4<<<dim3(NB * (NL / MI)), dim3(256), 0, stream>>>(
        q, k, v, s, bt, ri, (float*)d_out);
}

// Round 3
// 399.129 us; speedup vs baseline: 1.7756x; 1.7756x over previous
//
#include <hip/hip_runtime.h>

typedef _Float16 half8 __attribute__((ext_vector_type(8)));
typedef _Float16 half4 __attribute__((ext_vector_type(4)));
typedef float    floatx16 __attribute__((ext_vector_type(16)));

#define MFMA(a, b, c) __builtin_amdgcn_mfma_f32_32x32x16_f16((a), (b), (c), 0, 0, 0)

constexpr int NB = 32, NC = 256, NL = 1024, MI = 32, BJ = 32;
constexpr int NIT = NL / BJ;   // 32
constexpr int PSP = 33;

// LDS byte offsets (total 60032, launch_bounds(256,2) -> 2 blocks/CU, R0-proven regalloc)
constexpr int OFF_K    = 0;        // kF  f16 [16 ks][64 ls][8 t] = 16384
constexpr int OFF_V    = 16384;    // vF  f16 [8 ct][2 ksj][64 ls][8 t] = 16384 (swizzled granules)
constexpr int OFF_S    = 32768;    // sF  same = 16384
constexpr int OFF_PS   = 49152;    // pS  f32 [2 kh][32 i][33] = 8448
constexpr int OFF_PB   = 57600;    // pB  f16 [2 ksj][64 ls][8 t] = 2048
constexpr int OFF_ROWS = 59648;    // m/l/a rows 3*32*4 = 384
constexpr int SMEM_B   = 60032;

// Granule swizzle for vF/sF: XOR bits 5-6 of the granule index into bits 1-2 so the
// 4 jc-variants of one c-row land in different bank quads. Involution; write AND read.
__device__ __forceinline__ int swz(int g) { return g ^ (((g >> 5) & 3) << 1); }

// K staging: coalesced global reads (lanes sweep j), b128 frag writes (unchanged from R0).
__device__ __forceinline__ void stage_k(_Float16* kF, const float* kb, int tid) {
    #pragma unroll
    for (int r = 0; r < 4; ++r) {
        const int g = tid + r * 256, ks = g >> 6, ls = g & 63;
        const float* src = kb + (size_t)(ks * 16 + (ls >> 5) * 8) * NL + (ls & 31);
        half8 h;
        #pragma unroll
        for (int t = 0; t < 8; ++t) h[t] = (_Float16)src[(size_t)t * NL];
        *(half8*)(kF + g * 8) = h;
    }
}

// v/std staging: coalesced global reads (4 lanes per c-row), SWIZZLED b128 frag writes.
__device__ __forceinline__ void stage_a(_Float16* dst, const float* base, int tid) {
    #pragma unroll
    for (int r = 0; r < 4; ++r) {
        const int c = (tid >> 2) + r * 64, jc = tid & 3;
        const float* src = base + (size_t)c * NL + jc * 8;
        float4 a = *(const float4*)src;
        float4 b = *(const float4*)(src + 4);
        half8 h;
        h[0] = (_Float16)a.x; h[1] = (_Float16)a.y; h[2] = (_Float16)a.z; h[3] = (_Float16)a.w;
        h[4] = (_Float16)b.x; h[5] = (_Float16)b.y; h[6] = (_Float16)b.z; h[7] = (_Float16)b.w;
        const int gr = ((c >> 5) * 2 + (jc >> 1)) * 64 + (jc & 1) * 32 + (c & 31);
        *(half8*)(dst + swz(gr) * 8) = h;
    }
}

__global__ __launch_bounds__(256, 2)
void att_mfma5(const float* __restrict__ q,
               const float* __restrict__ kk,
               const float* __restrict__ v,
               const float* __restrict__ sd,
               const float* __restrict__ bt,
               const int* __restrict__ ri,
               float* __restrict__ out)
{
    (void)ri;   // rel_index is analytic: (yi-yj+31)*63 + (xi-xj+31)
    __shared__ __align__(16) char smem[SMEM_B];
    _Float16* kF   = (_Float16*)(smem + OFF_K);
    _Float16* vF   = (_Float16*)(smem + OFF_V);
    _Float16* sF   = (_Float16*)(smem + OFF_S);
    float*    pS   = (float*)(smem + OFF_PS);
    _Float16* pB   = (_Float16*)(smem + OFF_PB);
    float*    mrow = (float*)(smem + OFF_ROWS);
    float*    lrow = mrow + 32;
    float*    arow = mrow + 64;

    const int tid  = threadIdx.x;
    const int lane = tid & 63;
    const int wv   = tid >> 6;

    // XCD-locality swizzle: one batch's 32 i-blocks cluster on one XCD.
    const int bid = blockIdx.x;
    const int b   = (bid & 7) + ((bid >> 8) << 3);
    const int ib  = (bid >> 3) & 31;
    const int i0  = ib * MI;

    const float* kbase = kk + (size_t)b * NC * NL;
    const float* vbase = v  + (size_t)b * NC * NL;
    const float* sbase = sd + (size_t)b * NC * NL;

    // ---- Q A-fragments (hi/lo fp16), waves 0,1 only: kh = wv, ks = wv*8+kk2 ----
    half8 qhi[8], qlo[8];
    if (wv < 2) {
        const float* qb = q + (size_t)b * NC * NL + i0 + (lane & 31);
        #pragma unroll
        for (int kk2 = 0; kk2 < 8; ++kk2) {
            const int c0 = (wv * 8 + kk2) * 16 + (lane >> 5) * 8;
            #pragma unroll
            for (int t = 0; t < 8; ++t) {
                float x = qb[(size_t)(c0 + t) * NL];
                _Float16 h = (_Float16)x;
                qhi[kk2][t] = h;
                qlo[kk2][t] = (_Float16)(x - (float)h);
            }
        }
    }
    if (tid < 32) { mrow[tid] = -1e30f; lrow[tid] = 0.0f; arow[tid] = 1.0f; }

    // PV read offsets (half units), swizzled, loop-invariant
    int gA[2][2];
    #pragma unroll
    for (int d = 0; d < 2; ++d) {
        const int ct = wv * 2 + d;
        gA[d][0] = swz(ct * 128 + lane) * 8;
        gA[d][1] = swz(ct * 128 + 64 + lane) * 8;
    }

    floatx16 aV[2], aS[2];
    #pragma unroll
    for (int d = 0; d < 2; ++d)
        #pragma unroll
        for (int r = 0; r < 16; ++r) { aV[d][r] = 0.f; aS[d][r] = 0.f; }

    auto pv_step = [&]() {
        const float al = arow[lane & 31];
        if (!__all(al == 1.0f)) {   // exact: skip is bitwise-identical when max unchanged
            #pragma unroll
            for (int d = 0; d < 2; ++d)
                #pragma unroll
                for (int r = 0; r < 16; ++r) { aV[d][r] *= al; aS[d][r] *= al; }
        }
        half8 pb0 = *(const half8*)(pB + lane * 8);
        half8 pb1 = *(const half8*)(pB + (64 + lane) * 8);
        #pragma unroll
        for (int d = 0; d < 2; ++d) {
            half8 a0 = *(const half8*)(vF + gA[d][0]);
            half8 a1 = *(const half8*)(vF + gA[d][1]);
            aV[d] = MFMA(a0, pb0, aV[d]);
            aV[d] = MFMA(a1, pb1, aV[d]);
            half8 b0 = *(const half8*)(sF + gA[d][0]);
            half8 b1 = *(const half8*)(sF + gA[d][1]);
            aS[d] = MFMA(b0, pb0, aS[d]);
            aS[d] = MFMA(b1, pb1, aS[d]);
        }
    };

    stage_k(kF, kbase, tid);       // kF(0)
    __syncthreads();

    for (int it = 0; it < NIT; ++it) {
        const int j0 = it * BJ;

        // ---- PV(it-1): all waves, 2 c-tiles each ----
        if (it > 0) pv_step();

        // ---- scores(it): waves 0,1 (kh = wv) ----
        if (wv < 2) {
            floatx16 S;
            #pragma unroll
            for (int r = 0; r < 16; ++r) S[r] = 0.f;
            #pragma unroll
            for (int kk2 = 0; kk2 < 8; ++kk2) {
                const int ks = wv * 8 + kk2;
                half8 bf = *(const half8*)(kF + (ks * 64 + lane) * 8);
                S = MFMA(qhi[kk2], bf, S);
                S = MFMA(qlo[kk2], bf, S);
            }
            float* ps = pS + wv * 32 * PSP + (lane & 31);
            #pragma unroll
            for (int r = 0; r < 16; ++r) {
                int row = (r & 3) + 8 * (r >> 2) + 4 * (lane >> 5);
                ps[row * PSP] = S[r];
            }
        }
        __syncthreads();   // B1: pS ready; kF/vF/sF old reads done

        // ---- stage kF(it+1), vF/sF(it) ----
        if (it + 1 < NIT) stage_k(kF, kbase + j0 + BJ, tid);
        stage_a(vF, vbase + j0, tid);
        stage_a(sF, sbase + j0, tid);

        // ---- softmax(it): thread (i = tid>>3, s = tid&7) owns 4 cols ----
        {
            const int i = tid >> 3, s = tid & 7;
            const float* ps0 = pS + i * PSP + s * 4;
            // analytic bias: yi = ib, yj = it (i0, j0 both 32-aligned);
            // idx(x) = (ib-it+31)*63 + (i - (4s+x) + 31) -> 4 reverse-consecutive floats
            const float* bp = bt + (ib - it + 31) * 63 + (i - 4 * s + 28);
            float sc[4];
            sc[0] = ps0[0] + ps0[32 * PSP + 0] + bp[3];
            sc[1] = ps0[1] + ps0[32 * PSP + 1] + bp[2];
            sc[2] = ps0[2] + ps0[32 * PSP + 2] + bp[1];
            sc[3] = ps0[3] + ps0[32 * PSP + 3] + bp[0];
            float lm = fmaxf(fmaxf(sc[0], sc[1]), fmaxf(sc[2], sc[3]));
            lm = fmaxf(lm, __shfl_xor(lm, 1));
            lm = fmaxf(lm, __shfl_xor(lm, 2));
            lm = fmaxf(lm, __shfl_xor(lm, 4));
            const float mo = mrow[i];
            const float mn = fmaxf(lm, mo);
            float sum = 0.f;
            half4 ph;
            #pragma unroll
            for (int x = 0; x < 4; ++x) {
                float e = __expf(sc[x] - mn);
                sum += e;
                ph[x] = (_Float16)e;
            }
            sum += __shfl_xor(sum, 1);
            sum += __shfl_xor(sum, 2);
            sum += __shfl_xor(sum, 4);
            // pB frag: B[k=j][n=i], j = 4s..4s+3 -> ksj=s>>2, half=(s>>1)&1, t0=(s&1)*4
            *(half4*)(pB + (((s >> 2) * 64) + ((s >> 1) & 1) * 32 + i) * 8 + (s & 1) * 4) = ph;
            if (s == 0) {
                float al = __expf(mo - mn);   // == 1.0f exactly when mn == mo
                arow[i] = al;
                lrow[i] = lrow[i] * al + sum;
                mrow[i] = mn;
            }
        }
        __syncthreads();   // B2: pB/rows/kF(it+1)/vF/sF(it) ready
    }

    // ---- drain PV(NIT-1) ----
    pv_step();

    // ---- epilogue: normalize, LDS transpose (scr overlaps dead kF/vF), coalesced store ----
    const float linv = 1.0f / lrow[lane & 31];
    float* scr = (float*)smem;   // 256*33*4 = 33792 B
    __syncthreads();
    #pragma unroll
    for (int d = 0; d < 2; ++d) {
        const int ct = wv * 2 + d;
        #pragma unroll
        for (int r = 0; r < 16; ++r) {
            int c = ct * 32 + (r & 3) + 8 * (r >> 2) + 4 * (lane >> 5);
            scr[c * 33 + (lane & 31)] = aV[d][r] * linv;
        }
    }
    __syncthreads();
    {
        float* og = out + ((size_t)b * NC + tid) * NL + i0;
        #pragma unroll
        for (int g = 0; g < 8; ++g) {
            float4 o;
            o.x = scr[tid * 33 + g * 4 + 0];
            o.y = scr[tid * 33 + g * 4 + 1];
            o.z = scr[tid * 33 + g * 4 + 2];
            o.w = scr[tid * 33 + g * 4 + 3];
            *(float4*)(og + g * 4) = o;
        }
    }
    __syncthreads();
    #pragma unroll
    for (int d = 0; d < 2; ++d) {
        const int ct = wv * 2 + d;
        #pragma unroll
        for (int r = 0; r < 16; ++r) {
            int c = ct * 32 + (r & 3) + 8 * (r >> 2) + 4 * (lane >> 5);
            scr[c * 33 + (lane & 31)] = aS[d][r] * linv;
        }
    }
    __syncthreads();
    {
        float* og = out + (size_t)NB * NC * NL + ((size_t)b * NC + tid) * NL + i0;
        #pragma unroll
        for (int g = 0; g < 8; ++g) {
            float4 o;
            o.x = scr[tid * 33 + g * 4 + 0];
            o.y = scr[tid * 33 + g * 4 + 1];
            o.z = scr[tid * 33 + g * 4 + 2];
            o.w = scr[tid * 33 + g * 4 + 3];
            *(float4*)(og + g * 4) = o;
        }
    }
}

extern "C" void kernel_launch(void* const* d_in, const int* in_sizes, int n_in,
                              void* d_out, int out_size, void* d_ws, size_t ws_size,
                              hipStream_t stream)
{
    (void)in_sizes; (void)n_in; (void)d_ws; (void)ws_size; (void)out_size;
    const float* q  = (const float*)d_in[0];
    const float* k  = (const float*)d_in[1];
    const float* v  = (const float*)d_in[2];
    const float* s  = (const float*)d_in[3];
    const float* bt = (const float*)d_in[4];
    const int*   ri = (const int*)d_in[5];
    att_mfma5<<<dim3(NB * (NL / MI)), dim3(256), 0, stream>>>(
        q, k, v, s, bt, ri, (float*)d_out);
}